// Round 10
// baseline (220.758 us; speedup 1.0000x reference)
//
#include <hip/hip_runtime.h>
#include <stdint.h>

// BitConv1d: out = conv1d(x, sign(w), pad=1) * mean|w| * scale
// (x_scale cancels exactly: conv(x/s,w)*s == conv(x,w))
//
// r10 = r3 (141us champion) with HALVED barrier count: 4-deep LDS buffer
// rotation; each phase computes chunks {c,c+1} while staging {c+2,c+3};
// one s_barrier per 2 chunks (8 total vs 16). Phase writes touch buffers
// last read 2 chunks before the previous barrier -> race-free. b-prefetch
// regs reused sequentially (16 VGPR held) -> no r8-style spill.
//
// Workspace: float[1024] @0 partial |w| sums; float @4096 final factor;
//            ushort[786432] @8192 sign(w) bf16, layout [t][ci>>3][co][ci&7]

#define CIN   512
#define COUT  512
#define LLEN  4096
#define NBAT  16
#define KW    3
#define WELEMS (COUT*CIN*KW)

typedef __bf16 bf16x8 __attribute__((ext_vector_type(8)));
typedef float  f32x4  __attribute__((ext_vector_type(4)));

__device__ __forceinline__ uint32_t f2bf(float f) {
    union { float f; uint32_t u; } v; v.f = f;
    return (v.u + 0x7fffu + ((v.u >> 16) & 1u)) >> 16;   // RNE
}

// ---- pack sign(w) -> bf16 (MFMA layout) + per-block |w| partial sums ----
__global__ __launch_bounds__(256) void pack_w(const float* __restrict__ w,
                                              unsigned short* __restrict__ wsw,
                                              float* __restrict__ partial) {
    __shared__ float red[256];
    int tid = threadIdx.x;
    int idx = blockIdx.x * 256 + tid;          // co*512 + ci
    float s = 0.f;
    int co = idx >> 9, ci = idx & 511;
#pragma unroll
    for (int t = 0; t < KW; ++t) {
        float v = w[idx * 3 + t];
        s += fabsf(v);
        unsigned short b = (v > 0.f) ? 0x3F80 : ((v < 0.f) ? 0xBF80 : 0);
        wsw[((t * 64 + (ci >> 3)) * 512 + co) * 8 + (ci & 7)] = b;
    }
    red[tid] = s;
    __syncthreads();
    for (int off = 128; off > 0; off >>= 1) {
        if (tid < off) red[tid] += red[tid + off];
        __syncthreads();
    }
    if (tid == 0) partial[blockIdx.x] = red[0];
}

__global__ __launch_bounds__(256) void wscale_final(const float* __restrict__ partial,
                                                    const float* __restrict__ scale,
                                                    float* __restrict__ fac) {
    __shared__ float red[256];
    int tid = threadIdx.x;
    red[tid] = partial[tid] + partial[tid + 256] + partial[tid + 512] + partial[tid + 768];
    __syncthreads();
    for (int off = 128; off > 0; off >>= 1) {
        if (tid < off) red[tid] += red[tid + off];
        __syncthreads();
    }
    if (tid == 0) fac[0] = red[0] * (1.0f / (float)WELEMS) * scale[0];
}

// 128co x 128l block, 4 waves 2x2, wave-tile 64x64, acc 4x4, ci chunks of 32.
// B LDS: row ll 0..129, 64B/row (32 ci), slot kslot=ci>>3 XOR ((ll>>1)&3).
__global__ __launch_bounds__(256, 2) void conv_mfma(const float* __restrict__ x,
                                                    const unsigned short* __restrict__ wsw,
                                                    const float* __restrict__ fac,
                                                    float* __restrict__ out) {
    // XCD-aware bijective swizzle (2048 % 8 == 0): co-blocks sharing an x tile
    // run adjacent on one XCD.
    int swz = (blockIdx.x & 7) * 256 + (blockIdx.x >> 3);
    int cob = swz & 3;
    int lb  = (swz >> 2) & 31;
    int n   = swz >> 7;
    int co0 = cob * 128;
    int l0  = lb * 128;

    __shared__ char Bs[4][8320];    // 4-deep rotation, 33.3 KB

    int tid  = threadIdx.x;
    int wave = tid >> 6;
    int lane = tid & 63;
    int wco  = (wave >> 1) * 64;
    int wl   = (wave & 1) * 64;
    int m    = lane & 15;
    int ks   = lane >> 4;
    const int p  = tid & 15;      // ci pair (2p, 2p+1)
    const int fb = tid >> 4;      // float4 column

    const float* xbase = x + (size_t)(n * 512) * LLEN;
    const char*  wb    = (const char*)wsw;

    // A byte offsets: ((t*64 + c*4 + ks)*512 + co)*16
    int aoff[4];
#pragma unroll
    for (int ms = 0; ms < 4; ++ms)
        aoff[ms] = ks * 8192 + (co0 + wco + ms * 16 + m) * 16;

    // B prefetch regs (17 VGPR live, reused for each staged chunk)
    float4 b0[2], b1[2];
    float  hReg = 0.f;

    auto LOADB = [&](int c) {
        const float* xrow0 = xbase + (size_t)(c * 32 + 2 * p) * LLEN + l0;
        const float* xrow1 = xrow0 + LLEN;
        b0[0] = reinterpret_cast<const float4*>(xrow0)[fb];
        b1[0] = reinterpret_cast<const float4*>(xrow1)[fb];
        b0[1] = reinterpret_cast<const float4*>(xrow0)[fb + 16];
        b1[1] = reinterpret_cast<const float4*>(xrow1)[fb + 16];
        if (tid < 32)
            hReg = (l0 > 0) ? xbase[(size_t)(c * 32 + tid) * LLEN + l0 - 1] : 0.f;
        else if (tid < 64)
            hReg = (l0 + 128 < LLEN) ? xbase[(size_t)(c * 32 + tid - 32) * LLEN + l0 + 128] : 0.f;
    };
    auto WRITEB = [&](char* BsD) {
        int kslot = p >> 2, jj = (2 * p) & 7;
#pragma unroll
        for (int half = 0; half < 2; ++half) {
#pragma unroll
            for (int e = 0; e < 4; ++e) {
                int ll = (fb + half * 16) * 4 + 1 + e;        // 1..128
                uint32_t pk = f2bf(((const float*)&b0[half])[e])
                            | (f2bf(((const float*)&b1[half])[e]) << 16);
                *reinterpret_cast<uint32_t*>(
                    BsD + ll * 64 + ((kslot ^ ((ll >> 1) & 3)) << 4) + jj * 2) = pk;
            }
        }
        if (tid < 32) {
            *reinterpret_cast<unsigned short*>(
                BsD + ((tid >> 3) << 4) + (tid & 7) * 2) = (unsigned short)f2bf(hReg);
        } else if (tid < 64) {
            int ci = tid - 32, ll = 129;
            *reinterpret_cast<unsigned short*>(
                BsD + ll * 64 + (((ci >> 3) ^ ((ll >> 1) & 3)) << 4) + (ci & 7) * 2)
                = (unsigned short)f2bf(hReg);
        }
    };

    f32x4 acc[4][4];
#pragma unroll
    for (int i = 0; i < 4; ++i)
#pragma unroll
        for (int j = 0; j < 4; ++j) acc[i][j] = (f32x4){0.f, 0.f, 0.f, 0.f};

    auto COMPUTE = [&](int c) {
        const char* Bc = Bs[c & 3];
#pragma unroll
        for (int t = 0; t < KW; ++t) {
            bf16x8 afr[4], bfr[4];
            const char* ab = wb + t * 524288 + c * 32768;
#pragma unroll
            for (int ms = 0; ms < 4; ++ms)
                afr[ms] = *reinterpret_cast<const bf16x8*>(ab + aoff[ms]);
#pragma unroll
            for (int ns = 0; ns < 4; ++ns) {
                int ll = wl + ns * 16 + m + t;
                bfr[ns] = *reinterpret_cast<const bf16x8*>(
                    Bc + ll * 64 + ((ks ^ ((ll >> 1) & 3)) << 4));
            }
#pragma unroll
            for (int ms = 0; ms < 4; ++ms)
#pragma unroll
                for (int ns = 0; ns < 4; ++ns)
                    acc[ms][ns] = __builtin_amdgcn_mfma_f32_16x16x32_bf16(
                        afr[ms], bfr[ns], acc[ms][ns], 0, 0, 0);
        }
    };

    // prologue: stage chunks 0 and 1
    LOADB(0);
    WRITEB(Bs[0]);
    LOADB(1);
    WRITEB(Bs[1]);
    __syncthreads();

    // main: 8 phases, each computes {c, c+1}, stages {c+2, c+3}, ONE barrier
    for (int c = 0; c < 16; c += 2) {
        if (c + 2 < 16) LOADB(c + 2);
        __builtin_amdgcn_sched_barrier(0);     // loads issue before compute
        COMPUTE(c);
        if (c + 2 < 16) {
            WRITEB(Bs[(c + 2) & 3]);           // overwrites buffer of c-2 (fenced)
            LOADB(c + 3);                      // reuse b-regs just drained
        }
        __builtin_amdgcn_sched_barrier(0);
        COMPUTE(c + 1);
        if (c + 2 < 16) {
            WRITEB(Bs[(c + 3) & 3]);           // overwrites buffer of c-1 (fenced)
            asm volatile("s_waitcnt lgkmcnt(0)" ::: "memory");  // my ds_writes done
            __builtin_amdgcn_s_barrier();      // publish c+2, c+3
            __builtin_amdgcn_sched_barrier(0);
        }
    }

    // ---- epilogue: D lane map col=lane&15, row=(lane>>4)*4+r ----
    float fscale = fac[0];
    int r4 = (lane >> 4) * 4;
#pragma unroll
    for (int ms = 0; ms < 4; ++ms) {
#pragma unroll
        for (int ns = 0; ns < 4; ++ns) {
            int col  = l0 + wl + ns * 16 + m;
            int row0 = co0 + wco + ms * 16 + r4;
            float* o = out + ((size_t)(n * 512 + row0)) * LLEN + col;
#pragma unroll
            for (int r = 0; r < 4; ++r)
                o[(size_t)r * LLEN] = acc[ms][ns][r] * fscale;
        }
    }
}

extern "C" void kernel_launch(void* const* d_in, const int* in_sizes, int n_in,
                              void* d_out, int out_size, void* d_ws, size_t ws_size,
                              hipStream_t stream) {
    const float* x     = (const float*)d_in[0];
    const float* w     = (const float*)d_in[1];
    const float* scale = (const float*)d_in[2];
    float* out = (float*)d_out;

    float* partials = (float*)d_ws;                               // 1024 floats
    float* fac      = (float*)((char*)d_ws + 4096);               // 1 float
    unsigned short* wsw = (unsigned short*)((char*)d_ws + 8192);  // 786432 bf16

    pack_w<<<(COUT * CIN) / 256, 256, 0, stream>>>(w, wsw, partials);
    wscale_final<<<1, 256, 0, stream>>>(partials, scale, fac);
    conv_mfma<<<NBAT * 4 * 32, 256, 0, stream>>>(x, wsw, fac, out);
}

// Round 11
// 157.246 us; speedup vs baseline: 1.4039x; 1.4039x over previous
//
#include <hip/hip_runtime.h>
#include <stdint.h>

// BitConv1d: out = conv1d(x, sign(w), pad=1) * mean|w| * scale
// (x_scale cancels exactly: conv(x/s,w)*s == conv(x,w))
//
// r11: barrier-free streaming inner loop. Per block: 4 ci-quarters; each
// quarter stages [4 chunks][130 ll][64B] (33KB, r3-proven 64B-row swizzled
// layout -- r4's failure was its 1024B row stride, not the concept), then
// streams 4 chunks x 3 taps with ZERO barriers (A from L2, B from LDS).
// 8 sync events/block (vs 16); LDS 33KB + VGPR<=128 -> 4 independent
// blocks/CU so staging of one block hides under MFMA of the other three.
//
// Workspace: float[1024] @0 partial |w| sums; float @4096 final factor;
//            ushort[786432] @8192 sign(w) bf16, layout [t][ci>>3][co][ci&7]

#define CIN   512
#define COUT  512
#define LLEN  4096
#define NBAT  16
#define KW    3
#define WELEMS (COUT*CIN*KW)
#define BUFB  8336   // 8320 + 16B stagger (spreads staging-write banks)

typedef __bf16 bf16x8 __attribute__((ext_vector_type(8)));
typedef float  f32x4  __attribute__((ext_vector_type(4)));

__device__ __forceinline__ uint32_t f2bf(float f) {
    union { float f; uint32_t u; } v; v.f = f;
    return (v.u + 0x7fffu + ((v.u >> 16) & 1u)) >> 16;   // RNE
}

// ---- pack sign(w) -> bf16 (MFMA layout) + per-block |w| partial sums ----
__global__ __launch_bounds__(256) void pack_w(const float* __restrict__ w,
                                              unsigned short* __restrict__ wsw,
                                              float* __restrict__ partial) {
    __shared__ float red[256];
    int tid = threadIdx.x;
    int idx = blockIdx.x * 256 + tid;          // co*512 + ci
    float s = 0.f;
    int co = idx >> 9, ci = idx & 511;
#pragma unroll
    for (int t = 0; t < KW; ++t) {
        float v = w[idx * 3 + t];
        s += fabsf(v);
        unsigned short b = (v > 0.f) ? 0x3F80 : ((v < 0.f) ? 0xBF80 : 0);
        wsw[((t * 64 + (ci >> 3)) * 512 + co) * 8 + (ci & 7)] = b;
    }
    red[tid] = s;
    __syncthreads();
    for (int off = 128; off > 0; off >>= 1) {
        if (tid < off) red[tid] += red[tid + off];
        __syncthreads();
    }
    if (tid == 0) partial[blockIdx.x] = red[0];
}

__global__ __launch_bounds__(256) void wscale_final(const float* __restrict__ partial,
                                                    const float* __restrict__ scale,
                                                    float* __restrict__ fac) {
    __shared__ float red[256];
    int tid = threadIdx.x;
    red[tid] = partial[tid] + partial[tid + 256] + partial[tid + 512] + partial[tid + 768];
    __syncthreads();
    for (int off = 128; off > 0; off >>= 1) {
        if (tid < off) red[tid] += red[tid + off];
        __syncthreads();
    }
    if (tid == 0) fac[0] = red[0] * (1.0f / (float)WELEMS) * scale[0];
}

// 128co x 128l block, 4 waves 2x2, wave-tile 64x64, acc 4x4.
// B LDS per chunk: row ll 0..129 (64B = 32 ci), slot = (ci>>3) ^ ((ll>>1)&3).
__global__ __launch_bounds__(256, 4) void conv_mfma(const float* __restrict__ x,
                                                    const unsigned short* __restrict__ wsw,
                                                    const float* __restrict__ fac,
                                                    float* __restrict__ out) {
    // XCD-aware bijective swizzle (2048 % 8 == 0): co-blocks sharing an x tile
    // run adjacent on one XCD.
    int swz = (blockIdx.x & 7) * 256 + (blockIdx.x >> 3);
    int cob = swz & 3;
    int lb  = (swz >> 2) & 31;
    int n   = swz >> 7;
    int co0 = cob * 128;
    int l0  = lb * 128;

    __shared__ char Bs[4 * BUFB];   // 33344 B -> 4 blocks/CU

    int tid  = threadIdx.x;
    int wave = tid >> 6;
    int lane = tid & 63;
    int wco  = (wave >> 1) * 64;
    int wl   = (wave & 1) * 64;
    int m    = lane & 15;
    int ks   = lane >> 4;

    const float* xbase = x + (size_t)(n * 512) * LLEN;
    const char*  wb    = (const char*)wsw;

    // A byte offsets: ((t*64 + c*4 + ks)*512 + co)*16
    int aoff[4];
#pragma unroll
    for (int ms = 0; ms < 4; ++ms)
        aoff[ms] = ks * 8192 + (co0 + wco + ms * 16 + m) * 16;

    // staging ids: ci-pair sp (ci = 2sp,2sp+1 within quarter), l-half sh
    const int sp   = tid & 63;
    const int sh   = tid >> 6;
    const int scc  = sp >> 4;              // chunk within quarter
    const int sksl = (sp & 15) >> 2;       // ((2sp)&31)>>3
    const int sjj  = (2 * sp) & 7;

    auto STAGE = [&](int q) {
        size_t ci0 = (size_t)(q * 128 + 2 * sp);
        const float* r0 = xbase + ci0 * LLEN + l0 + sh * 32;
        const float* r1 = r0 + LLEN;
        char* base = Bs + scc * BUFB;
#pragma unroll
        for (int e = 0; e < 8; ++e) {
            float4 a = reinterpret_cast<const float4*>(r0)[e];
            float4 b = reinterpret_cast<const float4*>(r1)[e];
#pragma unroll
            for (int v = 0; v < 4; ++v) {
                int ll = sh * 32 + e * 4 + v + 1;             // 1..128
                uint32_t pk = f2bf(((const float*)&a)[v])
                            | (f2bf(((const float*)&b)[v]) << 16);
                *reinterpret_cast<uint32_t*>(
                    base + ll * 64 + ((sksl ^ ((ll >> 1) & 3)) << 4) + sjj * 2) = pk;
            }
        }
        if (sh == 0) {                                        // halo ll=0 (swz term 0)
            float a0 = 0.f, b0 = 0.f;
            if (l0 > 0) { a0 = xbase[ci0 * LLEN + l0 - 1];
                          b0 = xbase[(ci0 + 1) * LLEN + l0 - 1]; }
            *reinterpret_cast<uint32_t*>(base + (sksl << 4) + sjj * 2)
                = f2bf(a0) | (f2bf(b0) << 16);
        } else if (sh == 3) {                                 // halo ll=129 ((129>>1)&3==0)
            float a0 = 0.f, b0 = 0.f;
            if (l0 + 128 < LLEN) { a0 = xbase[ci0 * LLEN + l0 + 128];
                                   b0 = xbase[(ci0 + 1) * LLEN + l0 + 128]; }
            *reinterpret_cast<uint32_t*>(base + 129 * 64 + (sksl << 4) + sjj * 2)
                = f2bf(a0) | (f2bf(b0) << 16);
        }
    };

    f32x4 acc[4][4];
#pragma unroll
    for (int i = 0; i < 4; ++i)
#pragma unroll
        for (int j = 0; j < 4; ++j) acc[i][j] = (f32x4){0.f, 0.f, 0.f, 0.f};

    auto COMPUTE = [&](int c, int cc) {     // cc compile-time via unrolled caller
        const char* Bc = Bs + cc * BUFB;
#pragma unroll
        for (int t = 0; t < KW; ++t) {
            bf16x8 afr[4], bfr[4];
            const char* ab = wb + t * 524288 + c * 32768;
#pragma unroll
            for (int ms = 0; ms < 4; ++ms)
                afr[ms] = *reinterpret_cast<const bf16x8*>(ab + aoff[ms]);
#pragma unroll
            for (int ns = 0; ns < 4; ++ns) {
                int ll = wl + ns * 16 + m + t;
                bfr[ns] = *reinterpret_cast<const bf16x8*>(
                    Bc + ll * 64 + ((ks ^ ((ll >> 1) & 3)) << 4));
            }
#pragma unroll
            for (int ms = 0; ms < 4; ++ms)
#pragma unroll
                for (int ns = 0; ns < 4; ++ns)
                    acc[ms][ns] = __builtin_amdgcn_mfma_f32_16x16x32_bf16(
                        afr[ms], bfr[ns], acc[ms][ns], 0, 0, 0);
        }
    };

    for (int q = 0; q < 4; ++q) {
        if (q) __syncthreads();            // previous quarter's readers done
        STAGE(q);
        __syncthreads();                   // quarter published
#pragma unroll
        for (int cc = 0; cc < 4; ++cc)     // barrier-free streaming
            COMPUTE(q * 4 + cc, cc);
    }

    // ---- epilogue: D lane map col=lane&15, row=(lane>>4)*4+r ----
    float fscale = fac[0];
    int r4 = (lane >> 4) * 4;
#pragma unroll
    for (int ms = 0; ms < 4; ++ms) {
#pragma unroll
        for (int ns = 0; ns < 4; ++ns) {
            int col  = l0 + wl + ns * 16 + m;
            int row0 = co0 + wco + ms * 16 + r4;
            float* o = out + ((size_t)(n * 512 + row0)) * LLEN + col;
#pragma unroll
            for (int r = 0; r < 4; ++r)
                o[(size_t)r * LLEN] = acc[ms][ns][r] * fscale;
        }
    }
}

extern "C" void kernel_launch(void* const* d_in, const int* in_sizes, int n_in,
                              void* d_out, int out_size, void* d_ws, size_t ws_size,
                              hipStream_t stream) {
    const float* x     = (const float*)d_in[0];
    const float* w     = (const float*)d_in[1];
    const float* scale = (const float*)d_in[2];
    float* out = (float*)d_out;

    float* partials = (float*)d_ws;                               // 1024 floats
    float* fac      = (float*)((char*)d_ws + 4096);               // 1 float
    unsigned short* wsw = (unsigned short*)((char*)d_ws + 8192);  // 786432 bf16

    pack_w<<<(COUT * CIN) / 256, 256, 0, stream>>>(w, wsw, partials);
    wscale_final<<<1, 256, 0, stream>>>(partials, scale, fac);
    conv_mfma<<<NBAT * 4 * 32, 256, 0, stream>>>(x, wsw, fac, out);
}